// Round 11
// baseline (75.966 us; speedup 1.0000x reference)
//
#include <hip/hip_runtime.h>

// Batched Kalman filter, fully reduced:
//   B    = H @ phi                  (8x16)   Cphi = C @ phi       (8x16)
//   Sc   = H diag(Q) H^T + diag(R)  (8x8)    CQH  = C diag(Q) H^T (8x8)
//   T    = P0 @ B^T                 (16x8 per element)
//   S    = B @ T + Sc               (8x8 SPD)   y = z - B @ x0
//   w    = S^-1 y                   (redundant per-lane Cholesky, in-register)
//   out  = Cphi @ (x0 + T w) + CQH @ w
//
// Round 11 insight: per-wave DS-instruction count (~111 b128-class ops) x
// measured ds_read_b128 throughput (~8-12 cyc on the per-CU DS unit) fully
// reproduces the 68us plateau -> kernel is LDS-ISSUE-bound. Fix: move all
// wave-uniform matrix traffic off the DS pipe:
//   - pre-kernel derives B/BT/Cphi/Sc/CQH into d_ws once (512 floats);
//   - T-loop reads BT with compile-time-constant uniform indices -> s_load /
//     SGPR operand (scalar pipe, zero DS);
//   - row-i constants (B/Cphi/Sc/CQH rows) via vector global loads (VMEM
//     pipe, L1-hot) - zero DS;
//   - derive phase gone -> ZERO barriers; LDS = x0S + Tb only.
//
// Hard-won structure notes (earlier rounds):
//  - plain __launch_bounds__(256): a min-waves hint forced VGPR=40 and
//    ~470 MB scratch spill (round 2).
//  - Cross-lane per-element transport (T,S) via LDS b128; per-scalar
//    shuffles were ~4x DS issue, +22 us (round 4).
//  - In-register redundant Cholesky beats lane-cooperative GE by 12 us
//    (round 7).
//  - NO nontemporal loads: P0's lane-strided row ownership needs line reuse;
//    nt -> ~4x P0 HBM traffic, +26 us (round 8).

#define TS 132  // Tb element stride (words): 132 % 32 == 4 -> element groups rotate banks
#define XS 28   // x0S element stride (words)
#define TRI(a,k) ((a)*((a)+1)/2 + (k))

// d_ws layout (floats):
//   [0:128)   B row-major        [128:256) Cphi row-major
//   [256:320) Sc row-major       [320:384) CQH row-major
//   [384:512) BT: bt[k*8+m] = B[m][k]   (uniform s_load path)

__global__ __launch_bounds__(128) void kalman_derive(
    const float* __restrict__ phi,
    const float* __restrict__ Hm,
    const float* __restrict__ Cm,
    const float* __restrict__ Qd,
    const float* __restrict__ Rd,
    float* __restrict__ cst)
{
    const int tid = threadIdx.x;
    {
        const int m = tid >> 4, k = tid & 15;
        float bv = 0.f, cv = 0.f;
#pragma unroll
        for (int j = 0; j < 16; ++j) {
            const float pj = phi[j * 16 + k];
            bv += Hm[m * 16 + j] * pj;
            cv += Cm[m * 16 + j] * pj;
        }
        cst[m * 16 + k]        = bv;
        cst[128 + m * 16 + k]  = cv;
        cst[384 + k * 8 + m]   = bv;   // BT
    }
    if (tid < 64) {
        const int i2 = tid >> 3, j2 = tid & 7;
        float sc = (i2 == j2) ? Rd[i2] : 0.f;
        float cq = 0.f;
#pragma unroll
        for (int k = 0; k < 16; ++k) {
            const float qh = Qd[k] * Hm[j2 * 16 + k];
            sc += Hm[i2 * 16 + k] * qh;
            cq += Cm[i2 * 16 + k] * qh;
        }
        cst[256 + i2 * 8 + j2] = sc;
        cst[320 + i2 * 8 + j2] = cq;
    }
}

__global__ __launch_bounds__(256) void kalman_fused11(
    const float* __restrict__ z,
    const float* __restrict__ x0,
    const float* __restrict__ P0,
    const float* __restrict__ cst,
    float* __restrict__ out,
    int bs)
{
    __shared__ __align__(16) float x0S[32 * XS];  // words 0..15: x0 (later u); 16..23: y
    __shared__ __align__(16) float Tb[32 * TS];   // words 0..127: T rows (rows 0..7 reused for S)

    const int tid = threadIdx.x;
    const int e = tid >> 3;   // element in block (0..31)
    const int i = tid & 7;    // lane in element (0..7)
    long b = (long)blockIdx.x * 32 + e;
    const bool valid = (b < (long)bs);
    if (!valid) b = (long)bs - 1;

    // ---- per-element global loads issued first ----
    float4 Pq[8];
    {
        const float4* P0v = reinterpret_cast<const float4*>(P0 + (size_t)b * 256);
#pragma unroll
        for (int q = 0; q < 4; ++q) {
            Pq[q]     = P0v[i * 4 + q];
            Pq[q + 4] = P0v[(i + 8) * 4 + q];
        }
    }
    const float x0a = x0[b * 16 + i];
    const float x0b = x0[b * 16 + 8 + i];
    float yv = z[b * 8 + i];
    x0S[e * XS + i]     = x0a;
    x0S[e * XS + i + 8] = x0b;

    // ---- row-i constants via vector loads (L1-hot, VMEM pipe, zero DS) ----
    float br[16];
#pragma unroll
    for (int q = 0; q < 4; ++q) {
        const float4 A = *reinterpret_cast<const float4*>(&cst[i * 16 + 4 * q]);
        br[4*q+0] = A.x; br[4*q+1] = A.y; br[4*q+2] = A.z; br[4*q+3] = A.w;
    }

    // ---- T rows i, i+8: T[r][m] = sum_k P0[r][k] * BT[k][m] (BT uniform -> s_load) ----
    const float* __restrict__ BT = cst + 384;
    float t0[8], t1[8];
#pragma unroll
    for (int m = 0; m < 8; ++m) { t0[m] = 0.f; t1[m] = 0.f; }
#pragma unroll
    for (int q = 0; q < 4; ++q) {
        const float4 A = Pq[q], B4 = Pq[q + 4];
        const float a[4] = {A.x, A.y, A.z, A.w};
        const float c[4] = {B4.x, B4.y, B4.z, B4.w};
#pragma unroll
        for (int kk = 0; kk < 4; ++kk) {
            const int k = 4 * q + kk;
#pragma unroll
            for (int m = 0; m < 8; ++m) {
                const float Bkm = BT[k * 8 + m];   // uniform: compile-time offset
                t0[m] += a[kk] * Bkm;
                t1[m] += c[kk] * Bkm;
            }
        }
    }
    // stage T (intra-wave LDS round-trip; producer==consumer wave, no barrier)
    *reinterpret_cast<float4*>(&Tb[e * TS + i * 8 + 0]) = make_float4(t0[0], t0[1], t0[2], t0[3]);
    *reinterpret_cast<float4*>(&Tb[e * TS + i * 8 + 4]) = make_float4(t0[4], t0[5], t0[6], t0[7]);
    *reinterpret_cast<float4*>(&Tb[e * TS + (i + 8) * 8 + 0]) = make_float4(t1[0], t1[1], t1[2], t1[3]);
    *reinterpret_cast<float4*>(&Tb[e * TS + (i + 8) * 8 + 4]) = make_float4(t1[4], t1[5], t1[6], t1[7]);

    // ---- S row i = Sc[i,:] + B[i,:] @ T ----
    float s[8];
    {
        const float4 c0 = *reinterpret_cast<const float4*>(&cst[256 + i * 8 + 0]);
        const float4 c1 = *reinterpret_cast<const float4*>(&cst[256 + i * 8 + 4]);
        s[0]=c0.x; s[1]=c0.y; s[2]=c0.z; s[3]=c0.w; s[4]=c1.x; s[5]=c1.y; s[6]=c1.z; s[7]=c1.w;
    }
#pragma unroll
    for (int j = 0; j < 16; ++j) {
        const float4 ta = *reinterpret_cast<const float4*>(&Tb[e * TS + j * 8 + 0]);
        const float4 tb = *reinterpret_cast<const float4*>(&Tb[e * TS + j * 8 + 4]);
        const float bij = br[j];
        s[0] += bij*ta.x; s[1] += bij*ta.y; s[2] += bij*ta.z; s[3] += bij*ta.w;
        s[4] += bij*tb.x; s[5] += bij*tb.y; s[6] += bij*tb.z; s[7] += bij*tb.w;
    }

    // ---- y_i = z_i - B[i,:] @ x0 ----
#pragma unroll
    for (int q = 0; q < 4; ++q) {
        const float4 X = *reinterpret_cast<const float4*>(&x0S[e * XS + 4 * q]);
        yv -= br[4*q+0]*X.x + br[4*q+1]*X.y + br[4*q+2]*X.z + br[4*q+3]*X.w;
    }

    // ---- publish S row (over T rows 0-7; t0/t1 stay in regs) and y ----
    *reinterpret_cast<float4*>(&Tb[e * TS + i * 8 + 0]) = make_float4(s[0], s[1], s[2], s[3]);
    *reinterpret_cast<float4*>(&Tb[e * TS + i * 8 + 4]) = make_float4(s[4], s[5], s[6], s[7]);
    x0S[e * XS + 16 + i] = yv;

    // ---- read S lower triangle (12 b128 broadcast reads) + full y ----
    float L[36];
#pragma unroll
    for (int a = 0; a < 8; ++a) {
        const float4 q0 = *reinterpret_cast<const float4*>(&Tb[e * TS + a * 8 + 0]);
        L[TRI(a,0)] = q0.x;
        if (a >= 1) L[TRI(a,1)] = q0.y;
        if (a >= 2) L[TRI(a,2)] = q0.z;
        if (a >= 3) L[TRI(a,3)] = q0.w;
        if (a >= 4) {
            const float4 q1 = *reinterpret_cast<const float4*>(&Tb[e * TS + a * 8 + 4]);
            L[TRI(a,4)] = q1.x;
            if (a >= 5) L[TRI(a,5)] = q1.y;
            if (a >= 6) L[TRI(a,6)] = q1.z;
            if (a >= 7) L[TRI(a,7)] = q1.w;
        }
    }
    float yf[8];
    {
        const float4 ya = *reinterpret_cast<const float4*>(&x0S[e * XS + 16]);
        const float4 yb = *reinterpret_cast<const float4*>(&x0S[e * XS + 20]);
        yf[0]=ya.x; yf[1]=ya.y; yf[2]=ya.z; yf[3]=ya.w;
        yf[4]=yb.x; yf[5]=yb.y; yf[6]=yb.z; yf[7]=yb.w;
    }

    // ---- redundant in-register Cholesky (diag slots hold 1/sqrt) ----
#pragma unroll
    for (int k = 0; k < 8; ++k) {
        const float inv = __builtin_amdgcn_rsqf(L[TRI(k,k)]);
        L[TRI(k,k)] = inv;
#pragma unroll
        for (int a = k + 1; a < 8; ++a) L[TRI(a,k)] *= inv;
#pragma unroll
        for (int a = k + 1; a < 8; ++a) {
#pragma unroll
            for (int m = k + 1; m <= a; ++m)
                L[TRI(a,m)] -= L[TRI(a,k)] * L[TRI(m,k)];
        }
    }
    // forward + back solve, in place (w aliases yf)
#pragma unroll
    for (int a = 0; a < 8; ++a) {
        float t = yf[a];
#pragma unroll
        for (int j = 0; j < a; ++j) t -= L[TRI(a,j)] * yf[j];
        yf[a] = t * L[TRI(a,a)];
    }
#pragma unroll
    for (int a = 7; a >= 0; --a) {
        float t = yf[a];
#pragma unroll
        for (int j = a + 1; j < 8; ++j) t -= L[TRI(j,a)] * yf[j];
        yf[a] = t * L[TRI(a,a)];
    }
    // yf now holds w

    // ---- u rows = x0 + T w (t0/t1 from regs), publish u ----
    float th0 = 0.f, th1 = 0.f;
#pragma unroll
    for (int m = 0; m < 8; ++m) { th0 += t0[m] * yf[m]; th1 += t1[m] * yf[m]; }
    x0S[e * XS + i]     = x0a + th0;
    x0S[e * XS + i + 8] = x0b + th1;

    // ---- out[b][i] = Cphi[i,:] @ u + CQH[i,:] @ w (constants via VMEM) ----
    float oc = 0.f;
#pragma unroll
    for (int q = 0; q < 4; ++q) {
        const float4 A = *reinterpret_cast<const float4*>(&cst[128 + i * 16 + 4 * q]);
        const float4 U = *reinterpret_cast<const float4*>(&x0S[e * XS + 4 * q]);
        oc += A.x*U.x + A.y*U.y + A.z*U.z + A.w*U.w;
    }
    {
        const float4 q0 = *reinterpret_cast<const float4*>(&cst[320 + i * 8 + 0]);
        const float4 q1 = *reinterpret_cast<const float4*>(&cst[320 + i * 8 + 4]);
        oc += q0.x*yf[0] + q0.y*yf[1] + q0.z*yf[2] + q0.w*yf[3]
            + q1.x*yf[4] + q1.y*yf[5] + q1.z*yf[6] + q1.w*yf[7];
    }
    if (valid) out[b * 8 + i] = oc;
}

extern "C" void kernel_launch(void* const* d_in, const int* in_sizes, int n_in,
                              void* d_out, int out_size, void* d_ws, size_t ws_size,
                              hipStream_t stream)
{
    const float* z   = (const float*)d_in[0];
    const float* x0  = (const float*)d_in[1];
    const float* P0  = (const float*)d_in[2];
    const float* phi = (const float*)d_in[3];
    const float* H   = (const float*)d_in[4];
    const float* C   = (const float*)d_in[5];
    const float* Qd  = (const float*)d_in[6];
    const float* Rd  = (const float*)d_in[7];
    float* out = (float*)d_out;
    float* cst = (float*)d_ws;               // 512 floats

    const int bs = in_sizes[0] / 8;          // z is [bs, 8]
    const int blocks = (bs + 31) / 32;       // 32 elements per block

    hipLaunchKernelGGL(kalman_derive, dim3(1), dim3(128), 0, stream,
                       phi, H, C, Qd, Rd, cst);
    hipLaunchKernelGGL(kalman_fused11, dim3(blocks), dim3(256), 0, stream,
                       z, x0, P0, cst, out, bs);
}

// Round 12
// 70.161 us; speedup vs baseline: 1.0827x; 1.0827x over previous
//
#include <hip/hip_runtime.h>

// Batched Kalman filter, fully reduced:
//   B    = H @ phi                  (8x16)   Cphi = C @ phi       (8x16)
//   Sc   = H diag(Q) H^T + diag(R)  (8x8)    CQH  = C diag(Q) H^T (8x8)
//   T    = P0 @ B^T                 (16x8 per element)
//   S    = B @ T + Sc               (8x8 SPD)   y = z - B @ x0
//   w    = S^-1 y                   (redundant per-lane Cholesky, in-register)
//   out  = Cphi @ (x0 + T w) + CQH @ w
// 8 threads per element (thread i owns rows i, i+8), 32 elements per
// 256-thread block. ONE barrier (constants). Cross-lane transport is
// intra-wave LDS b128 round-trips (ds-ordered, barrier-free).
//
// Round 12: v_pk_fma_f32 (packed fp32, VOP3P — the compiler never emits it;
// scalar-FMA uBench = 103 TF vs 157 TF packed). T-loop and S-build use
// m-adjacent accumulator PAIRS so the multiplier pair comes directly from
// the b128-loaded float4 (zero broadcast movs for the vector operand):
//   T: 256 fma -> 128 pk_fma + 32 movs;  S: 128 fma -> 64 pk_fma + 16 movs.
//
// Hard-won structure notes (earlier rounds):
//  - plain __launch_bounds__(256): min-waves hint -> VGPR=40, ~470 MB spill
//    traffic (round 2). Never.
//  - Cross-lane matrix transport via LDS b128; per-scalar shuffles ~4x DS
//    issue, +22 us (round 4).
//  - In-register redundant Cholesky beats lane-cooperative GE by 12 us (r7).
//  - NO nontemporal loads: P0's lane-strided row ownership needs line reuse;
//    nt -> ~4x P0 HBM traffic, +26 us (round 8).
//  - Pre-kernel for constants: +8 us serial dependency; derive-in-block is
//    free under the P0 load latency (round 11).

#define TS 132  // Tb element stride (words): 132 % 32 == 4 -> element groups rotate banks
#define XS 28   // x0S element stride (words)
#define TRI(a,k) ((a)*((a)+1)/2 + (k))

typedef float v2f __attribute__((ext_vector_type(2)));

static __device__ __forceinline__ v2f pkfma(v2f a, v2f b, v2f c) {
    v2f d;
    asm("v_pk_fma_f32 %0, %1, %2, %3" : "=v"(d) : "v"(a), "v"(b), "v"(c));
    return d;
}

__global__ __launch_bounds__(256) void kalman_fused12(
    const float* __restrict__ z,
    const float* __restrict__ x0,
    const float* __restrict__ P0,
    const float* __restrict__ phi,
    const float* __restrict__ Hm,
    const float* __restrict__ Cm,
    const float* __restrict__ Qd,
    const float* __restrict__ Rd,
    float* __restrict__ out,
    int bs)
{
    __shared__ __align__(16) float BnS[8 * 20];   // B rows, stride 20
    __shared__ __align__(16) float BTS[16 * 8];   // BTS[k*8+m] = B[m][k] (broadcast reads)
    __shared__ __align__(16) float CpS[8 * 20];   // Cphi rows, stride 20
    __shared__ __align__(16) float CQHS[8 * 8];   // CQH rows
    __shared__ __align__(16) float ScS[8 * 8];    // Sc rows
    __shared__ __align__(16) float x0S[32 * XS];  // words 0..15: x0 (later u); 16..23: y
    __shared__ __align__(16) float Tb[32 * TS];   // words 0..127: T rows (rows 0..7 reused for S)

    const int tid = threadIdx.x;
    const int e = tid >> 3;   // element in block (0..31)
    const int i = tid & 7;    // lane in element (0..7)
    long b = (long)blockIdx.x * 32 + e;
    const bool valid = (b < (long)bs);
    if (!valid) b = (long)bs - 1;

    // ---- per-element global loads issued first (latency hides under derive) ----
    float4 Pq[8];
    {
        const float4* P0v = reinterpret_cast<const float4*>(P0 + (size_t)b * 256);
#pragma unroll
        for (int q = 0; q < 4; ++q) {
            Pq[q]     = P0v[i * 4 + q];
            Pq[q + 4] = P0v[(i + 8) * 4 + q];
        }
    }
    const float x0a = x0[b * 16 + i];
    const float x0b = x0[b * 16 + 8 + i];
    float yv = z[b * 8 + i];
    x0S[e * XS + i]     = x0a;
    x0S[e * XS + i + 8] = x0b;

    // ---- derive per-block constants straight from global (tiny, cache-hot) ----
    if (tid < 128) {
        const int m = tid >> 4, k = tid & 15;
        float bv = 0.f, cv = 0.f;
#pragma unroll
        for (int j = 0; j < 16; ++j) {
            const float pj = phi[j * 16 + k];
            bv += Hm[m * 16 + j] * pj;
            cv += Cm[m * 16 + j] * pj;
        }
        BnS[m * 20 + k] = bv;
        BTS[k * 8 + m]  = bv;
        CpS[m * 20 + k] = cv;
    }
    if (tid < 64) {
        const int i2 = tid >> 3, j2 = tid & 7;
        float sc = (i2 == j2) ? Rd[i2] : 0.f;
        float cq = 0.f;
#pragma unroll
        for (int k = 0; k < 16; ++k) {
            const float qh = Qd[k] * Hm[j2 * 16 + k];
            sc += Hm[i2 * 16 + k] * qh;
            cq += Cm[i2 * 16 + k] * qh;
        }
        ScS[i2 * 8 + j2]  = sc;
        CQHS[i2 * 8 + j2] = cq;
    }
    __syncthreads();  // the ONLY barrier

    // ---- T rows i, i+8 via packed FMA: pairs over adjacent m ----
    // tp0[p] = (T[i][2p], T[i][2p+1]) ; tp1[p] = (T[i+8][2p], T[i+8][2p+1])
    v2f tp0[4], tp1[4];
#pragma unroll
    for (int p = 0; p < 4; ++p) { tp0[p] = (v2f)(0.f); tp1[p] = (v2f)(0.f); }
#pragma unroll
    for (int q = 0; q < 4; ++q) {
        const float4 A = Pq[q], B4 = Pq[q + 4];
        const float a[4] = {A.x, A.y, A.z, A.w};
        const float c[4] = {B4.x, B4.y, B4.z, B4.w};
#pragma unroll
        for (int kk = 0; kk < 4; ++kk) {
            const int k = 4 * q + kk;
            const float4 b0v = *reinterpret_cast<const float4*>(&BTS[k * 8 + 0]);
            const float4 b1v = *reinterpret_cast<const float4*>(&BTS[k * 8 + 4]);
            const v2f bp0 = {b0v.x, b0v.y}, bp1 = {b0v.z, b0v.w};
            const v2f bp2 = {b1v.x, b1v.y}, bp3 = {b1v.z, b1v.w};
            const v2f av = {a[kk], a[kk]};
            const v2f cv = {c[kk], c[kk]};
            tp0[0] = pkfma(av, bp0, tp0[0]); tp0[1] = pkfma(av, bp1, tp0[1]);
            tp0[2] = pkfma(av, bp2, tp0[2]); tp0[3] = pkfma(av, bp3, tp0[3]);
            tp1[0] = pkfma(cv, bp0, tp1[0]); tp1[1] = pkfma(cv, bp1, tp1[1]);
            tp1[2] = pkfma(cv, bp2, tp1[2]); tp1[3] = pkfma(cv, bp3, tp1[3]);
        }
    }
    // stage T (intra-wave round-trip; producer==consumer wave, no barrier)
    *reinterpret_cast<float4*>(&Tb[e * TS + i * 8 + 0]) =
        make_float4(tp0[0].x, tp0[0].y, tp0[1].x, tp0[1].y);
    *reinterpret_cast<float4*>(&Tb[e * TS + i * 8 + 4]) =
        make_float4(tp0[2].x, tp0[2].y, tp0[3].x, tp0[3].y);
    *reinterpret_cast<float4*>(&Tb[e * TS + (i + 8) * 8 + 0]) =
        make_float4(tp1[0].x, tp1[0].y, tp1[1].x, tp1[1].y);
    *reinterpret_cast<float4*>(&Tb[e * TS + (i + 8) * 8 + 4]) =
        make_float4(tp1[2].x, tp1[2].y, tp1[3].x, tp1[3].y);

    // ---- B row i -> regs ----
    float br[16];
#pragma unroll
    for (int q = 0; q < 4; ++q) {
        const float4 A = *reinterpret_cast<const float4*>(&BnS[i * 20 + 4 * q]);
        br[4*q+0] = A.x; br[4*q+1] = A.y; br[4*q+2] = A.z; br[4*q+3] = A.w;
    }

    // ---- S row i = Sc[i,:] + B[i,:] @ T (packed pairs over adjacent j-cols) ----
    v2f sp[4];
    {
        const float4 c0 = *reinterpret_cast<const float4*>(&ScS[i * 8 + 0]);
        const float4 c1 = *reinterpret_cast<const float4*>(&ScS[i * 8 + 4]);
        sp[0] = (v2f){c0.x, c0.y}; sp[1] = (v2f){c0.z, c0.w};
        sp[2] = (v2f){c1.x, c1.y}; sp[3] = (v2f){c1.z, c1.w};
    }
#pragma unroll
    for (int j = 0; j < 16; ++j) {
        const float4 ta = *reinterpret_cast<const float4*>(&Tb[e * TS + j * 8 + 0]);
        const float4 tb = *reinterpret_cast<const float4*>(&Tb[e * TS + j * 8 + 4]);
        const v2f bv = {br[j], br[j]};
        sp[0] = pkfma(bv, (v2f){ta.x, ta.y}, sp[0]);
        sp[1] = pkfma(bv, (v2f){ta.z, ta.w}, sp[1]);
        sp[2] = pkfma(bv, (v2f){tb.x, tb.y}, sp[2]);
        sp[3] = pkfma(bv, (v2f){tb.z, tb.w}, sp[3]);
    }

    // ---- y_i = z_i - B[i,:] @ x0 ----
#pragma unroll
    for (int q = 0; q < 4; ++q) {
        const float4 X = *reinterpret_cast<const float4*>(&x0S[e * XS + 4 * q]);
        yv -= br[4*q+0]*X.x + br[4*q+1]*X.y + br[4*q+2]*X.z + br[4*q+3]*X.w;
    }

    // ---- publish S row (over T rows 0-7; tp stays in regs for tail) and y ----
    *reinterpret_cast<float4*>(&Tb[e * TS + i * 8 + 0]) =
        make_float4(sp[0].x, sp[0].y, sp[1].x, sp[1].y);
    *reinterpret_cast<float4*>(&Tb[e * TS + i * 8 + 4]) =
        make_float4(sp[2].x, sp[2].y, sp[3].x, sp[3].y);
    x0S[e * XS + 16 + i] = yv;

    // ---- read S lower triangle (12 b128 broadcast reads) + full y ----
    float L[36];
#pragma unroll
    for (int a = 0; a < 8; ++a) {
        const float4 q0 = *reinterpret_cast<const float4*>(&Tb[e * TS + a * 8 + 0]);
        L[TRI(a,0)] = q0.x;
        if (a >= 1) L[TRI(a,1)] = q0.y;
        if (a >= 2) L[TRI(a,2)] = q0.z;
        if (a >= 3) L[TRI(a,3)] = q0.w;
        if (a >= 4) {
            const float4 q1 = *reinterpret_cast<const float4*>(&Tb[e * TS + a * 8 + 4]);
            L[TRI(a,4)] = q1.x;
            if (a >= 5) L[TRI(a,5)] = q1.y;
            if (a >= 6) L[TRI(a,6)] = q1.z;
            if (a >= 7) L[TRI(a,7)] = q1.w;
        }
    }
    float yf[8];
    {
        const float4 ya = *reinterpret_cast<const float4*>(&x0S[e * XS + 16]);
        const float4 yb = *reinterpret_cast<const float4*>(&x0S[e * XS + 20]);
        yf[0]=ya.x; yf[1]=ya.y; yf[2]=ya.z; yf[3]=ya.w;
        yf[4]=yb.x; yf[5]=yb.y; yf[6]=yb.z; yf[7]=yb.w;
    }

    // ---- redundant in-register Cholesky (diag slots hold 1/sqrt) ----
#pragma unroll
    for (int k = 0; k < 8; ++k) {
        const float inv = __builtin_amdgcn_rsqf(L[TRI(k,k)]);
        L[TRI(k,k)] = inv;
#pragma unroll
        for (int a = k + 1; a < 8; ++a) L[TRI(a,k)] *= inv;
#pragma unroll
        for (int a = k + 1; a < 8; ++a) {
#pragma unroll
            for (int m = k + 1; m <= a; ++m)
                L[TRI(a,m)] -= L[TRI(a,k)] * L[TRI(m,k)];
        }
    }
    // forward + back solve, in place (w aliases yf)
#pragma unroll
    for (int a = 0; a < 8; ++a) {
        float t = yf[a];
#pragma unroll
        for (int j = 0; j < a; ++j) t -= L[TRI(a,j)] * yf[j];
        yf[a] = t * L[TRI(a,a)];
    }
#pragma unroll
    for (int a = 7; a >= 0; --a) {
        float t = yf[a];
#pragma unroll
        for (int j = a + 1; j < 8; ++j) t -= L[TRI(j,a)] * yf[j];
        yf[a] = t * L[TRI(a,a)];
    }
    // yf now holds w

    // ---- u rows = x0 + T w (tp pairs still live), publish u ----
    float th0 = 0.f, th1 = 0.f;
#pragma unroll
    for (int p = 0; p < 4; ++p) {
        th0 += tp0[p].x * yf[2*p] + tp0[p].y * yf[2*p+1];
        th1 += tp1[p].x * yf[2*p] + tp1[p].y * yf[2*p+1];
    }
    x0S[e * XS + i]     = x0a + th0;
    x0S[e * XS + i + 8] = x0b + th1;

    // ---- out[b][i] = Cphi[i,:] @ u + CQH[i,:] @ w ----
    float oc = 0.f;
#pragma unroll
    for (int q = 0; q < 4; ++q) {
        const float4 A = *reinterpret_cast<const float4*>(&CpS[i * 20 + 4 * q]);
        const float4 U = *reinterpret_cast<const float4*>(&x0S[e * XS + 4 * q]);
        oc += A.x*U.x + A.y*U.y + A.z*U.z + A.w*U.w;
    }
    {
        const float4 q0 = *reinterpret_cast<const float4*>(&CQHS[i * 8 + 0]);
        const float4 q1 = *reinterpret_cast<const float4*>(&CQHS[i * 8 + 4]);
        oc += q0.x*yf[0] + q0.y*yf[1] + q0.z*yf[2] + q0.w*yf[3]
            + q1.x*yf[4] + q1.y*yf[5] + q1.z*yf[6] + q1.w*yf[7];
    }
    if (valid) out[b * 8 + i] = oc;
}

extern "C" void kernel_launch(void* const* d_in, const int* in_sizes, int n_in,
                              void* d_out, int out_size, void* d_ws, size_t ws_size,
                              hipStream_t stream)
{
    const float* z   = (const float*)d_in[0];
    const float* x0  = (const float*)d_in[1];
    const float* P0  = (const float*)d_in[2];
    const float* phi = (const float*)d_in[3];
    const float* H   = (const float*)d_in[4];
    const float* C   = (const float*)d_in[5];
    const float* Qd  = (const float*)d_in[6];
    const float* Rd  = (const float*)d_in[7];
    float* out = (float*)d_out;

    const int bs = in_sizes[0] / 8;          // z is [bs, 8]
    const int blocks = (bs + 31) / 32;       // 32 elements per block
    hipLaunchKernelGGL(kalman_fused12, dim3(blocks), dim3(256), 0, stream,
                       z, x0, P0, phi, H, C, Qd, Rd, out, bs);
}

// Round 13
// 68.974 us; speedup vs baseline: 1.1014x; 1.0172x over previous
//
#include <hip/hip_runtime.h>

// Batched Kalman filter, fully reduced (FINAL, best-measured structure = round 7, 68.1 us):
//   B    = H @ phi                  (8x16)   Cphi = C @ phi       (8x16)
//   Sc   = H diag(Q) H^T + diag(R)  (8x8)    CQH  = C diag(Q) H^T (8x8)
//   T    = P0 @ B^T                 (16x8 per element)
//   S    = B @ T + Sc               (8x8 SPD, min-eig >= R = 0.1)
//   y    = z - B @ x0
//   w    = S^-1 y                   (redundant per-lane Cholesky, in-register)
//   out  = Cphi @ (x0 + T w) + CQH @ w
// 8 threads per element (thread i owns rows i, i+8), 32 elements per
// 256-thread block. ONE barrier (constants). All cross-lane transport is
// intra-wave LDS b128 round-trips (ds-ordered, barrier-free); group-of-8
// same-address reads broadcast (cheap).
//
// Optimization ledger (12 rounds):
//  - P_new / P_pred / x_new never formed; tail folded into Cphi/CQH  (147->87)
//  - barrier-free streaming after 2-barrier prologue                 (87->80)
//  - in-register redundant Cholesky vs lane-cooperative GE           (80->68)
//  - NEUTRAL at ~68: occupancy diet (r10), constants via VMEM/SGPR (r11),
//    v_pk_fma_f32 packing (r12), in-place solve (r9)
//  - REGRESSIONS (reverted): min-waves launch_bounds -> spills (r2, +124);
//    per-scalar shuffle transport (r4, +22); grid-stride prologue
//    amortization (r6, +3); nontemporal P0 loads (r8, +26: lane-strided
//    row ownership needs cache-line reuse); pre-kernel constants (r11, +8).
// Multi-pipe balance at 68 us: HBM/L3 ~45-48, DS ~25, VALU ~16 with
// imperfect overlap — no single pipe dominates; 4 independent single-pipe
// levers all came back neutral.

#define QFMA(ACC, OFF, A, V) { ACC[(OFF)+0] += (A)*(V).x; ACC[(OFF)+1] += (A)*(V).y; ACC[(OFF)+2] += (A)*(V).z; ACC[(OFF)+3] += (A)*(V).w; }
#define TS 132  // Tb element stride (words): 132 % 32 == 4 -> element groups rotate banks
#define XS 28   // x0S element stride (words)
#define TRI(a,k) ((a)*((a)+1)/2 + (k))

__global__ __launch_bounds__(256) void kalman_final(
    const float* __restrict__ z,
    const float* __restrict__ x0,
    const float* __restrict__ P0,
    const float* __restrict__ phi,
    const float* __restrict__ Hm,
    const float* __restrict__ Cm,
    const float* __restrict__ Qd,
    const float* __restrict__ Rd,
    float* __restrict__ out,
    int bs)
{
    __shared__ __align__(16) float BnS[8 * 20];   // B rows, stride 20
    __shared__ __align__(16) float BTS[16 * 8];   // BTS[k*8+m] = B[m][k] (broadcast reads)
    __shared__ __align__(16) float CpS[8 * 20];   // Cphi rows, stride 20
    __shared__ __align__(16) float CQHS[8 * 8];   // CQH rows
    __shared__ __align__(16) float ScS[8 * 8];    // Sc rows
    __shared__ __align__(16) float x0S[32 * XS];  // words 0..15: x0 (later u); 16..23: y
    __shared__ __align__(16) float Tb[32 * TS];   // words 0..127: T rows (rows 0..7 reused for S)

    const int tid = threadIdx.x;
    const int e = tid >> 3;   // element in block (0..31)
    const int i = tid & 7;    // lane in element (0..7)
    long b = (long)blockIdx.x * 32 + e;
    const bool valid = (b < (long)bs);
    if (!valid) b = (long)bs - 1;

    // ---- per-element global loads issued first (latency hides under derive) ----
    float4 Pq[8];
    {
        const float4* P0v = reinterpret_cast<const float4*>(P0 + (size_t)b * 256);
#pragma unroll
        for (int q = 0; q < 4; ++q) {
            Pq[q]     = P0v[i * 4 + q];
            Pq[q + 4] = P0v[(i + 8) * 4 + q];
        }
    }
    const float x0a = x0[b * 16 + i];
    const float x0b = x0[b * 16 + 8 + i];
    float yv = z[b * 8 + i];
    x0S[e * XS + i]     = x0a;
    x0S[e * XS + i + 8] = x0b;

    // ---- derive per-block constants straight from global (tiny, cache-hot) ----
    if (tid < 128) {
        const int m = tid >> 4, k = tid & 15;
        float bv = 0.f, cv = 0.f;
#pragma unroll
        for (int j = 0; j < 16; ++j) {
            const float pj = phi[j * 16 + k];
            bv += Hm[m * 16 + j] * pj;
            cv += Cm[m * 16 + j] * pj;
        }
        BnS[m * 20 + k] = bv;
        BTS[k * 8 + m]  = bv;
        CpS[m * 20 + k] = cv;
    }
    if (tid < 64) {
        const int i2 = tid >> 3, j2 = tid & 7;
        float sc = (i2 == j2) ? Rd[i2] : 0.f;
        float cq = 0.f;
#pragma unroll
        for (int k = 0; k < 16; ++k) {
            const float qh = Qd[k] * Hm[j2 * 16 + k];
            sc += Hm[i2 * 16 + k] * qh;
            cq += Cm[i2 * 16 + k] * qh;
        }
        ScS[i2 * 8 + j2]  = sc;
        CQHS[i2 * 8 + j2] = cq;
    }
    __syncthreads();  // the ONLY barrier

    // ---- T rows i, i+8: T[r][m] = sum_k P0[r][k] * B[m][k] ----
    float t0[8], t1[8];
#pragma unroll
    for (int m = 0; m < 8; ++m) { t0[m] = 0.f; t1[m] = 0.f; }
#pragma unroll
    for (int q = 0; q < 4; ++q) {
        const float4 A = Pq[q], B4 = Pq[q + 4];
        const float a[4] = {A.x, A.y, A.z, A.w};
        const float c[4] = {B4.x, B4.y, B4.z, B4.w};
#pragma unroll
        for (int kk = 0; kk < 4; ++kk) {
            const int k = 4 * q + kk;
            const float4 b0v = *reinterpret_cast<const float4*>(&BTS[k * 8 + 0]);
            const float4 b1v = *reinterpret_cast<const float4*>(&BTS[k * 8 + 4]);
            QFMA(t0, 0, a[kk], b0v) QFMA(t0, 4, a[kk], b1v)
            QFMA(t1, 0, c[kk], b0v) QFMA(t1, 4, c[kk], b1v)
        }
    }
    // stage T (intra-wave round-trip; producer==consumer wave, no barrier)
    *reinterpret_cast<float4*>(&Tb[e * TS + i * 8 + 0]) = make_float4(t0[0], t0[1], t0[2], t0[3]);
    *reinterpret_cast<float4*>(&Tb[e * TS + i * 8 + 4]) = make_float4(t0[4], t0[5], t0[6], t0[7]);
    *reinterpret_cast<float4*>(&Tb[e * TS + (i + 8) * 8 + 0]) = make_float4(t1[0], t1[1], t1[2], t1[3]);
    *reinterpret_cast<float4*>(&Tb[e * TS + (i + 8) * 8 + 4]) = make_float4(t1[4], t1[5], t1[6], t1[7]);

    // ---- B row i -> regs ----
    float br[16];
#pragma unroll
    for (int q = 0; q < 4; ++q) {
        const float4 A = *reinterpret_cast<const float4*>(&BnS[i * 20 + 4 * q]);
        br[4*q+0] = A.x; br[4*q+1] = A.y; br[4*q+2] = A.z; br[4*q+3] = A.w;
    }

    // ---- S row i = Sc[i,:] + B[i,:] @ T (broadcast reads of all T rows) ----
    float s[8];
    {
        const float4 c0 = *reinterpret_cast<const float4*>(&ScS[i * 8 + 0]);
        const float4 c1 = *reinterpret_cast<const float4*>(&ScS[i * 8 + 4]);
        s[0]=c0.x; s[1]=c0.y; s[2]=c0.z; s[3]=c0.w; s[4]=c1.x; s[5]=c1.y; s[6]=c1.z; s[7]=c1.w;
    }
#pragma unroll
    for (int j = 0; j < 16; ++j) {
        const float4 ta = *reinterpret_cast<const float4*>(&Tb[e * TS + j * 8 + 0]);
        const float4 tb = *reinterpret_cast<const float4*>(&Tb[e * TS + j * 8 + 4]);
        const float bij = br[j];
        QFMA(s, 0, bij, ta) QFMA(s, 4, bij, tb)
    }

    // ---- y_i = z_i - B[i,:] @ x0 ----
#pragma unroll
    for (int q = 0; q < 4; ++q) {
        const float4 X = *reinterpret_cast<const float4*>(&x0S[e * XS + 4 * q]);
        yv -= br[4*q+0]*X.x + br[4*q+1]*X.y + br[4*q+2]*X.z + br[4*q+3]*X.w;
    }

    // ---- publish S row (reuse Tb rows 0-7: all T reads above are done) and y ----
    *reinterpret_cast<float4*>(&Tb[e * TS + i * 8 + 0]) = make_float4(s[0], s[1], s[2], s[3]);
    *reinterpret_cast<float4*>(&Tb[e * TS + i * 8 + 4]) = make_float4(s[4], s[5], s[6], s[7]);
    x0S[e * XS + 16 + i] = yv;

    // ---- read S lower triangle (12 b128 broadcast reads) + full y ----
    float L[36];
#pragma unroll
    for (int a = 0; a < 8; ++a) {
        const float4 q0 = *reinterpret_cast<const float4*>(&Tb[e * TS + a * 8 + 0]);
        L[TRI(a,0)] = q0.x;
        if (a >= 1) L[TRI(a,1)] = q0.y;
        if (a >= 2) L[TRI(a,2)] = q0.z;
        if (a >= 3) L[TRI(a,3)] = q0.w;
        if (a >= 4) {
            const float4 q1 = *reinterpret_cast<const float4*>(&Tb[e * TS + a * 8 + 4]);
            L[TRI(a,4)] = q1.x;
            if (a >= 5) L[TRI(a,5)] = q1.y;
            if (a >= 6) L[TRI(a,6)] = q1.z;
            if (a >= 7) L[TRI(a,7)] = q1.w;
        }
    }
    float yf[8];
    {
        const float4 ya = *reinterpret_cast<const float4*>(&x0S[e * XS + 16]);
        const float4 yb = *reinterpret_cast<const float4*>(&x0S[e * XS + 20]);
        yf[0]=ya.x; yf[1]=ya.y; yf[2]=ya.z; yf[3]=ya.w;
        yf[4]=yb.x; yf[5]=yb.y; yf[6]=yb.z; yf[7]=yb.w;
    }

    // ---- redundant in-register Cholesky (diag slots hold 1/sqrt after step) ----
#pragma unroll
    for (int k = 0; k < 8; ++k) {
        const float inv = __builtin_amdgcn_rsqf(L[TRI(k,k)]);
        L[TRI(k,k)] = inv;
#pragma unroll
        for (int a = k + 1; a < 8; ++a) L[TRI(a,k)] *= inv;
#pragma unroll
        for (int a = k + 1; a < 8; ++a) {
#pragma unroll
            for (int m = k + 1; m <= a; ++m)
                L[TRI(a,m)] -= L[TRI(a,k)] * L[TRI(m,k)];
        }
    }
    // forward solve L y' = y, then back solve L^T w = y' (in place)
#pragma unroll
    for (int a = 0; a < 8; ++a) {
        float t = yf[a];
#pragma unroll
        for (int j = 0; j < a; ++j) t -= L[TRI(a,j)] * yf[j];
        yf[a] = t * L[TRI(a,a)];
    }
#pragma unroll
    for (int a = 7; a >= 0; --a) {
        float t = yf[a];
#pragma unroll
        for (int j = a + 1; j < 8; ++j) t -= L[TRI(j,a)] * yf[j];
        yf[a] = t * L[TRI(a,a)];
    }
    // yf now holds w

    // ---- u rows = x0 + T w (registers), publish u ----
    float th0 = 0.f, th1 = 0.f;
#pragma unroll
    for (int m = 0; m < 8; ++m) { th0 += t0[m] * yf[m]; th1 += t1[m] * yf[m]; }
    x0S[e * XS + i]     = x0a + th0;
    x0S[e * XS + i + 8] = x0b + th1;

    // ---- out[b][i] = Cphi[i,:] @ u + CQH[i,:] @ w ----
    float oc = 0.f;
#pragma unroll
    for (int q = 0; q < 4; ++q) {
        const float4 A = *reinterpret_cast<const float4*>(&CpS[i * 20 + 4 * q]);
        const float4 U = *reinterpret_cast<const float4*>(&x0S[e * XS + 4 * q]);
        oc += A.x*U.x + A.y*U.y + A.z*U.z + A.w*U.w;
    }
    {
        const float4 q0 = *reinterpret_cast<const float4*>(&CQHS[i * 8 + 0]);
        const float4 q1 = *reinterpret_cast<const float4*>(&CQHS[i * 8 + 4]);
        oc += q0.x*yf[0] + q0.y*yf[1] + q0.z*yf[2] + q0.w*yf[3]
            + q1.x*yf[4] + q1.y*yf[5] + q1.z*yf[6] + q1.w*yf[7];
    }
    if (valid) out[b * 8 + i] = oc;
}

extern "C" void kernel_launch(void* const* d_in, const int* in_sizes, int n_in,
                              void* d_out, int out_size, void* d_ws, size_t ws_size,
                              hipStream_t stream)
{
    const float* z   = (const float*)d_in[0];
    const float* x0  = (const float*)d_in[1];
    const float* P0  = (const float*)d_in[2];
    const float* phi = (const float*)d_in[3];
    const float* H   = (const float*)d_in[4];
    const float* C   = (const float*)d_in[5];
    const float* Qd  = (const float*)d_in[6];
    const float* Rd  = (const float*)d_in[7];
    float* out = (float*)d_out;

    const int bs = in_sizes[0] / 8;          // z is [bs, 8]
    const int blocks = (bs + 31) / 32;       // 32 elements per block
    hipLaunchKernelGGL(kalman_final, dim3(blocks), dim3(256), 0, stream,
                       z, x0, P0, phi, H, C, Qd, Rd, out, bs);
}